// Round 5
// baseline (165.298 us; speedup 1.0000x reference)
//
#include <hip/hip_runtime.h>

#define BQ  8
#define NQ  100
#define HWP 65536
#define TILE 128
#define KST  32          // K columns per iteration
#define RSTRIDE 64       // A(32 cols) | B(32 cols) fused -> 128B LDS rows

typedef float  f32x4  __attribute__((ext_vector_type(4)));
typedef __bf16 bf16x8 __attribute__((ext_vector_type(8)));

struct LD { float4 x, y; };

__device__ __forceinline__ uint32_t pk2(float a, float b) {
    // RNE fp32 -> bf16, packed pair
    uint32_t ua = __builtin_bit_cast(uint32_t, a);
    uint32_t ub = __builtin_bit_cast(uint32_t, b);
    ua += 0x7FFFu + ((ua >> 16) & 1u);
    ub += 0x7FFFu + ((ub >> 16) & 1u);
    return (ua >> 16) | (ub & 0xFFFF0000u);
}

__device__ __forceinline__ LD ldrow(const float* __restrict__ base, int row, int pofs) {
    LD r;
    if (row < NQ) {
        const float4* p = (const float4*)(base + (size_t)row * HWP + pofs);
        r.x = p[0];
        r.y = p[1];
    } else {
        r.x = make_float4(0.f, 0.f, 0.f, 0.f);
        r.y = make_float4(0.f, 0.f, 0.f, 0.f);
    }
    return r;
}

// 8 floats -> 8 bf16 (16B) into slot (slotLog ^ row&7) of the 128B row.
// Same XOR mapping on write and read keeps A/B access 2-way-free on banks.
__device__ __forceinline__ void st16(unsigned short* buf, int row, int slotLog, const LD& v) {
    const int slot = slotLog ^ (row & 7);
    uint4 u;
    u.x = pk2(v.x.x, v.x.y);
    u.y = pk2(v.x.z, v.x.w);
    u.z = pk2(v.y.x, v.y.y);
    u.w = pk2(v.y.z, v.y.w);
    *(uint4*)(buf + row * RSTRIDE + slot * 8) = u;
}

__device__ __forceinline__ float sqsum(const LD& v) {
    return v.x.x*v.x.x + v.x.y*v.x.y + v.x.z*v.x.z + v.x.w*v.x.w
         + v.y.x*v.y.x + v.y.y*v.y.y + v.y.z*v.y.z + v.y.w*v.y.w;
}

__device__ __forceinline__ void mfma_step(const unsigned short* __restrict__ rX,
                                          int lane, int wr, int wc,
                                          f32x4 (&acc)[2][4])
{
    const int kk = lane >> 4;          // logical 16B slot (K-subchunk)
    bf16x8 af[2];
    bf16x8 bfr[4];
    #pragma unroll
    for (int m = 0; m < 2; ++m) {
        const int r = wr * 32 + m * 16 + (lane & 15);
        const int sl = kk ^ (r & 7);
        af[m] = *(const bf16x8*)(rX + r * RSTRIDE + sl * 8);
    }
    #pragma unroll
    for (int n = 0; n < 4; ++n) {
        const int r = wc * 64 + n * 16 + (lane & 15);
        const int sl = (kk | 4) ^ (r & 7);
        bfr[n] = *(const bf16x8*)(rX + r * RSTRIDE + sl * 8);
    }
    #pragma unroll
    for (int m = 0; m < 2; ++m)
        #pragma unroll
        for (int n = 0; n < 4; ++n)
            acc[m][n] = __builtin_amdgcn_mfma_f32_16x16x32_bf16(
                af[m], bfr[n], acc[m][n], 0, 0, 0);
}

// One block = (batch, P-chunk). 128x128 partial Gram tile + row norms.
// KEY CHANGE vs R1-R4: raw s_barrier + lgkmcnt(0) only — no __syncthreads,
// whose compiler-emitted vmcnt(0) drained the register prefetch every
// iteration and serialized issue-burst -> drain -> compute (43% mem duty).
// 2-deep prefetch now genuinely spans two barriers (~1000cy > HBM latency).
__global__ __launch_bounds__(512, 2) void matcher_gemm(
    const float* __restrict__ mp, const float* __restrict__ mg,
    float* __restrict__ dotp, float* __restrict__ normA, float* __restrict__ normB,
    int NC, int NIT)
{
    __shared__ __align__(16) unsigned short lds_buf[2][TILE * RSTRIDE]; // 32 KiB

    const int blk  = blockIdx.x;
    const int b    = blk / NC;
    const int slot = blk - b * NC;
    const int p0   = slot * NIT * KST;

    const int t    = threadIdx.x;
    const int lane = t & 63;
    const int w    = t >> 6;      // wave 0..7
    const int row  = t >> 2;      // 0..127 (= w*16 + lane>>2)
    const int q    = t & 3;       // 8-float quad within the 32-col window
    const int wr   = w >> 1;      // 0..3 -> 32-row strip of C
    const int wc   = w & 1;       // 0..1 -> 64-col strip of C
    const int coff = q * 8;

    const float* Ag = mp + (size_t)b * NQ * HWP;
    const float* Bg = mg + (size_t)b * NQ * HWP;

    f32x4 acc[2][4] = {};
    float nA = 0.f, nB = 0.f;

    // two named prefetch stages (static indexing — rule #20)
    LD a0 = ldrow(Ag, row, p0 + coff);
    LD b0 = ldrow(Bg, row, p0 + coff);
    LD a1 = ldrow(Ag, row, p0 + KST + coff);
    LD b1 = ldrow(Bg, row, p0 + KST + coff);

    for (int it = 0; it < NIT; it += 2) {
        // ---- even K-step: stage S0 -> buf0 ----
        st16(lds_buf[0], row, q,     a0);
        st16(lds_buf[0], row, q | 4, b0);
        nA += sqsum(a0); nB += sqsum(b0);
        if (it + 2 < NIT) {
            const int pofs = p0 + (it + 2) * KST + coff;
            a0 = ldrow(Ag, row, pofs);
            b0 = ldrow(Bg, row, pofs);
        }
        asm volatile("s_waitcnt lgkmcnt(0)" ::: "memory"); // LDS visibility only
        __builtin_amdgcn_s_barrier();                      // vmem stays in flight
        mfma_step(lds_buf[0], lane, wr, wc, acc);

        // ---- odd K-step: stage S1 -> buf1 ----
        st16(lds_buf[1], row, q,     a1);
        st16(lds_buf[1], row, q | 4, b1);
        nA += sqsum(a1); nB += sqsum(b1);
        if (it + 3 < NIT) {
            const int pofs = p0 + (it + 3) * KST + coff;
            a1 = ldrow(Ag, row, pofs);
            b1 = ldrow(Bg, row, pofs);
        }
        asm volatile("s_waitcnt lgkmcnt(0)" ::: "memory");
        __builtin_amdgcn_s_barrier();
        mfma_step(lds_buf[1], lane, wr, wc, acc);
    }

    // per-row norms: 4 quad-threads per row are adjacent lanes
    nA += __shfl_xor(nA, 1); nA += __shfl_xor(nA, 2);
    nB += __shfl_xor(nB, 1); nB += __shfl_xor(nB, 2);
    if ((lane & 3) == 0) {
        normA[(size_t)blk * TILE + row] = nA;
        normB[(size_t)blk * TILE + row] = nB;
    }

    // C/D layout (HW-verified): col = lane&15, row = (lane>>4)*4 + reg
    float* dp = dotp + (size_t)blk * (TILE * TILE);
    const int ccol = lane & 15;
    const int crow = (lane >> 4) * 4;
    #pragma unroll
    for (int m = 0; m < 2; ++m) {
        #pragma unroll
        for (int n = 0; n < 4; ++n) {
            const int gr = wr * 32 + m * 16 + crow;
            const int gc = wc * 64 + n * 16 + ccol;
            #pragma unroll
            for (int j = 0; j < 4; ++j)
                dp[(size_t)(gr + j) * TILE + gc] = acc[m][n][j];
        }
    }
}

// Reduce chunk partials, apply class-agreement term and dice division.
__global__ __launch_bounds__(256) void matcher_finalize(
    const float* __restrict__ y_p, const float* __restrict__ y_gt,
    const float* __restrict__ dotp, const float* __restrict__ normA,
    const float* __restrict__ normB, float* __restrict__ out, int NC)
{
    __shared__ float sA[TILE];
    __shared__ float sB[TILE];
    const int b    = blockIdx.x >> 4;
    const int part = blockIdx.x & 15;
    const int t    = threadIdx.x;

    if (t < TILE) {
        float s = 0.f;
        for (int c = 0; c < NC; ++c) s += normA[(size_t)(b * NC + c) * TILE + t];
        sA[t] = s;
    } else {
        float s = 0.f;
        for (int c = 0; c < NC; ++c) s += normB[(size_t)(b * NC + c) * TILE + (t - TILE)];
        sB[t - TILE] = s;
    }
    __syncthreads();

    for (int i = t; i < 625; i += 256) {
        const int idx = part * 625 + i;           // 0..9999 within batch
        const int n = idx / 100;
        const int k = idx - n * 100;
        float dot = 0.f;
        for (int c = 0; c < NC; ++c)
            dot += dotp[(size_t)(b * NC + c) * (TILE * TILE) + n * TILE + k];
        const float yp = y_p[b * NQ + n];
        const float yg = y_gt[b * NQ + k];
        const float t1 = yp * yg + (1.f - yp) * (1.f - yg);
        out[(size_t)b * (NQ * NQ) + idx] = t1 * (2.f * dot) / (sA[n] + sB[k]);
    }
}

extern "C" void kernel_launch(void* const* d_in, const int* in_sizes, int n_in,
                              void* d_out, int out_size, void* d_ws, size_t ws_size,
                              hipStream_t stream)
{
    const float* y_p  = (const float*)d_in[0];
    const float* y_gt = (const float*)d_in[1];
    const float* m_p  = (const float*)d_in[2];
    const float* m_gt = (const float*)d_in[3];
    float* out = (float*)d_out;

    // NC=64 -> 512 blocks (2/CU at 32 KiB LDS), ws 34 MB (confirmed fits in R3)
    int NC = 64;
    while (NC > 1) {
        size_t need = (size_t)BQ * NC * (TILE * TILE + 2 * TILE) * sizeof(float);
        if (need <= ws_size) break;
        NC >>= 1;
    }
    const int NIT = (HWP / NC) / KST;

    float* dotp  = (float*)d_ws;
    float* normA = dotp + (size_t)BQ * NC * TILE * TILE;
    float* normB = normA + (size_t)BQ * NC * TILE;

    matcher_gemm<<<dim3(BQ * NC), dim3(512), 0, stream>>>(
        m_p, m_gt, dotp, normA, normB, NC, NIT);
    matcher_finalize<<<dim3(BQ * 16), dim3(256), 0, stream>>>(
        y_p, y_gt, dotp, normA, normB, out, NC);
}